// Round 1
// baseline (81.196 us; speedup 1.0000x reference)
//
#include <hip/hip_runtime.h>
#include <math.h>

// Problem constants (fixed by reference setup_inputs)
#define BB 128
#define LL 512
#define DD 256
#define TT 64
#define GG 8   // LL / TT

__device__ __forceinline__ float sigm(float x) {
    return 1.0f / (1.0f + __expf(-x));
}

// Kernel 1: group-pool both modalities, compute c_att and hw, row-mean of hw over D.
// grid = BB*TT blocks, 256 threads (one per d)
__global__ void k_pool(const float* __restrict__ aco, const float* __restrict__ vis,
                       const float* __restrict__ conv_w, const float* __restrict__ conv_b,
                       float* __restrict__ c_att, float* __restrict__ hw_buf,
                       float* __restrict__ hwRowMean)
{
    const int bt = blockIdx.x;      // b*TT + t
    const int d  = threadIdx.x;     // 0..255
    const int b  = bt >> 6;         // / TT
    const int t  = bt & 63;

    size_t base = ((size_t)(b * LL + t * GG)) * DD + d;
    float sa = 0.f, sv = 0.f;
#pragma unroll
    for (int g = 0; g < GG; ++g) {
        sa += aco[base + (size_t)g * DD];
        sv += vis[base + (size_t)g * DD];
    }
    sa *= (1.0f / GG);
    sv *= (1.0f / GG);

    const float cw0 = conv_w[0], cw1 = conv_w[1], cb = conv_b[0];
    const float hw = 0.5f * (sa + sv);

    c_att[(size_t)bt * DD + d]  = sigm(cw0 * sa + cw1 * sv + cb);
    hw_buf[(size_t)bt * DD + d] = hw;

    __shared__ float red[DD];
    red[d] = hw;
    __syncthreads();
    for (int s = DD / 2; s > 0; s >>= 1) {
        if (d < s) red[d] += red[d + s];
        __syncthreads();
    }
    if (d == 0) hwRowMean[bt] = red[0] * (1.0f / DD);
}

// Kernel 2: h_att = sigmoid(hwRowMean @ Wh^T + bh). grid = BB, block = TT
__global__ void k_hatt(const float* __restrict__ hwRowMean, const float* __restrict__ Wh,
                       const float* __restrict__ bh, float* __restrict__ h_att)
{
    const int b = blockIdx.x;
    const int t = threadIdx.x;  // 0..63
    __shared__ float row[TT];
    row[t] = hwRowMean[b * TT + t];
    __syncthreads();
    float s = bh[t];
#pragma unroll
    for (int j = 0; j < TT; ++j) s += row[j] * Wh[t * TT + j];
    h_att[b * TT + t] = sigm(s);
}

// Kernel 3: col-mean of hw over T, then w_att = sigmoid(colMean @ Ww^T + bw).
// grid = BB, block = DD
__global__ void k_watt(const float* __restrict__ hw_buf, const float* __restrict__ Ww,
                       const float* __restrict__ bw, float* __restrict__ w_att)
{
    const int b = blockIdx.x;
    const int d = threadIdx.x;  // 0..255
    float s = 0.f;
    const float* hb = hw_buf + (size_t)b * TT * DD + d;
#pragma unroll
    for (int t = 0; t < TT; ++t) s += hb[(size_t)t * DD];

    __shared__ float cm[DD];
    cm[d] = s * (1.0f / TT);
    __syncthreads();

    float acc = bw[d];
    const float* wr = Ww + (size_t)d * DD;
#pragma unroll 4
    for (int k = 0; k < DD; k += 4) {
        float4 w4 = *reinterpret_cast<const float4*>(wr + k);
        acc += cm[k] * w4.x + cm[k + 1] * w4.y + cm[k + 2] * w4.z + cm[k + 3] * w4.w;
    }
    w_att[b * DD + d] = sigm(acc);
}

// Kernel 4: apply scale to both streams. One float4 per thread.
__global__ void k_apply(const float* __restrict__ aco, const float* __restrict__ vis,
                        const int* __restrict__ isbag,
                        const float* __restrict__ c_att, const float* __restrict__ h_att,
                        const float* __restrict__ w_att,
                        float* __restrict__ out)
{
    const size_t N4 = (size_t)BB * LL * DD / 4;
    size_t i = (size_t)blockIdx.x * blockDim.x + threadIdx.x;
    if (i >= N4) return;

    const int row = (int)(i >> 6);   // DD/4 = 64 float4 per row
    const int dq  = (int)(i & 63);   // float4 index within row
    const int b   = row >> 9;        // / LL
    const int l   = row & 511;
    const int t   = l >> 3;          // / GG

    const float h  = h_att[b * TT + t];
    const float4 w4 = *reinterpret_cast<const float4*>(w_att + b * DD + dq * 4);
    const float4 c4 = *reinterpret_cast<const float4*>(c_att + ((size_t)(b * TT + t)) * DD + dq * 4);
    const bool  m  = (isbag[row] == 1);

    const float4 a4 = reinterpret_cast<const float4*>(aco)[i];
    const float4 v4 = reinterpret_cast<const float4*>(vis)[i];

    const float inv3 = 1.0f / 3.0f;
    float4 s4;
    s4.x = (h + w4.x + c4.x) * inv3;
    s4.y = (h + w4.y + c4.y) * inv3;
    s4.z = (h + w4.z + c4.z) * inv3;
    s4.w = (h + w4.w + c4.w) * inv3;

    float4 oa, ov;
    oa.x = m ? a4.x * s4.x : a4.x;
    oa.y = m ? a4.y * s4.y : a4.y;
    oa.z = m ? a4.z * s4.z : a4.z;
    oa.w = m ? a4.w * s4.w : a4.w;
    ov.x = m ? v4.x * s4.x : v4.x;
    ov.y = m ? v4.y * s4.y : v4.y;
    ov.z = m ? v4.z * s4.z : v4.z;
    ov.w = m ? v4.w * s4.w : v4.w;

    reinterpret_cast<float4*>(out)[i]      = oa;
    reinterpret_cast<float4*>(out)[N4 + i] = ov;
}

extern "C" void kernel_launch(void* const* d_in, const int* in_sizes, int n_in,
                              void* d_out, int out_size, void* d_ws, size_t ws_size,
                              hipStream_t stream) {
    const float* aco = (const float*)d_in[0];
    const float* vis = (const float*)d_in[1];
    const int*   isb = (const int*)d_in[2];
    const float* Wh  = (const float*)d_in[3];
    const float* bh  = (const float*)d_in[4];
    const float* Ww  = (const float*)d_in[5];
    const float* bw  = (const float*)d_in[6];
    const float* cw  = (const float*)d_in[7];
    const float* cb  = (const float*)d_in[8];
    float* out = (float*)d_out;

    float* ws = (float*)d_ws;
    float* c_att     = ws;                              // BB*TT*DD = 2M floats
    float* hw_buf    = c_att  + (size_t)BB * TT * DD;   // BB*TT*DD
    float* hwRowMean = hw_buf + (size_t)BB * TT * DD;   // BB*TT
    float* h_att     = hwRowMean + BB * TT;             // BB*TT
    float* w_att     = h_att + BB * TT;                 // BB*DD

    k_pool<<<BB * TT, DD, 0, stream>>>(aco, vis, cw, cb, c_att, hw_buf, hwRowMean);
    k_hatt<<<BB, TT, 0, stream>>>(hwRowMean, Wh, bh, h_att);
    k_watt<<<BB, DD, 0, stream>>>(hw_buf, Ww, bw, w_att);

    const size_t N4 = (size_t)BB * LL * DD / 4;
    k_apply<<<(int)(N4 / 256), 256, 0, stream>>>(aco, vis, isb, c_att, h_att, w_att, out);
}